// Round 1
// baseline (660.869 us; speedup 1.0000x reference)
//
#include <hip/hip_runtime.h>
#include <math.h>

#define DEV __device__ __forceinline__

typedef __bf16 bf16x8 __attribute__((ext_vector_type(8)));
typedef float f32x4 __attribute__((ext_vector_type(4)));

typedef const __attribute__((address_space(1))) void gv_t;
typedef __attribute__((address_space(3))) void lv_t;

DEV unsigned short f2bf(float f){
  unsigned int u = __float_as_uint(f);
  u += 0x7fffu + ((u >> 16) & 1u);     // round-to-nearest-even
  return (unsigned short)(u >> 16);
}

DEV void gload16(const void* g, void* l){
  __builtin_amdgcn_global_load_lds((gv_t*)g, (lv_t*)l, 16, 0, 0);
}

// ---------------------------------------------------------------------------
// C[M,N] = A[M,K] (bf16, row-major, lda) * B^T  (B given as [N][K] bf16, ldb)
// CMODE: 0 = f32 store (+bias), 1 = bf16 store (+bias), 2 = bf16 gelu(+bias),
//        3 = bf16 scatter to vT[B=8][H=8][512][512]  (m=(b,s), n=(h,ko))
// Batched over blockIdx.z: z = b*8+h, operand offsets in ELEMENTS.
// All dims multiples of 128 (M,N) / 32 (K): no bounds checks.
// ---------------------------------------------------------------------------
template<int CMODE>
__global__ __launch_bounds__(256, 2)
void gemm_bt(const unsigned short* __restrict__ A, const unsigned short* __restrict__ B,
             void* __restrict__ C, const float* __restrict__ bias,
             int M, int N, int K, int lda, int ldb, int ldc,
             size_t aOffH, size_t aOffB, size_t bOffH, size_t bOffB,
             size_t cOffH, size_t cOffB)
{
  __shared__ unsigned short At[128*32];
  __shared__ unsigned short Bt[128*32];
  const int z = blockIdx.z, bb = z >> 3, hh = z & 7;
  A += (size_t)bb*aOffB + (size_t)hh*aOffH;
  B += (size_t)bb*bOffB + (size_t)hh*bOffH;
  const size_t coff = (size_t)bb*cOffB + (size_t)hh*cOffH;

  const int tid = threadIdx.x, w = tid >> 6, lane = tid & 63;
  const int wr = w >> 1, wc = w & 1;
  const int m0 = blockIdx.y*128, n0 = blockIdx.x*128;

  f32x4 acc[4][4] = {};

  const int srow = lane >> 2;        // row within 16-row chunk
  const int scol = (lane & 3) * 8;   // element offset within 32-elem row

  for (int kt = 0; kt < K; kt += 32){
    if (kt) __syncthreads();
    #pragma unroll
    for (int j = 0; j < 2; j++){
      const int c = w*2 + j;                 // chunk 0..7 (16 rows each)
      const int r = c*16 + srow;
      gload16(A + (size_t)(m0 + r)*lda + kt + scol, &At[c*512]);
      gload16(B + (size_t)(n0 + r)*ldb + kt + scol, &Bt[c*512]);
    }
    __syncthreads();
    bf16x8 af[4], bfr[4];
    const int kq = (lane >> 4) * 8;
    #pragma unroll
    for (int i = 0; i < 4; i++){
      af[i]  = *(const bf16x8*)&At[(wr*64 + i*16 + (lane & 15))*32 + kq];
      bfr[i] = *(const bf16x8*)&Bt[(wc*64 + i*16 + (lane & 15))*32 + kq];
    }
    #pragma unroll
    for (int i = 0; i < 4; i++)
      #pragma unroll
      for (int jj = 0; jj < 4; jj++)
        acc[i][jj] = __builtin_amdgcn_mfma_f32_16x16x32_bf16(af[i], bfr[jj], acc[i][jj], 0, 0, 0);
  }

  // Epilogue. C/D frag layout (verified, guide §3): col = lane&15, row = (lane>>4)*4 + reg.
  #pragma unroll
  for (int i = 0; i < 4; i++){
    const int mbase = m0 + wr*64 + i*16 + ((lane >> 4) << 2);
    #pragma unroll
    for (int jj = 0; jj < 4; jj++){
      const int n = n0 + wc*64 + jj*16 + (lane & 15);
      const float bv = bias ? bias[n] : 0.0f;
      #pragma unroll
      for (int r = 0; r < 4; r++){
        const int m = mbase + r;
        float v = acc[i][jj][r] + bv;
        if (CMODE == 0){
          ((float*)C)[coff + (size_t)m*ldc + n] = v;
        } else if (CMODE == 1){
          ((unsigned short*)C)[coff + (size_t)m*ldc + n] = f2bf(v);
        } else if (CMODE == 2){
          v = 0.5f * v * (1.0f + erff(v * 0.70710678118654752f));   // exact GELU
          ((unsigned short*)C)[coff + (size_t)m*ldc + n] = f2bf(v);
        } else {
          // vT[b][h][ko][s]: b=m>>9, s=m&511, h=n>>9, ko=n&511
          const size_t addr = (((size_t)((m >> 9)*8 + (n >> 9))*512) + (size_t)(n & 511))*512
                              + (size_t)(m & 511);
          ((unsigned short*)C)[addr] = f2bf(v);
        }
      }
    }
  }
}

// ---------------------------------------------------------------------------
// Row softmax over scores [64][512][512] f32, in-place; writes bf16 probs into
// the first 1024 bytes of each 2048-byte row (so probs lda = 1024 ushorts).
// One wave per row; scale = 1/sqrt(512) applied here.
// ---------------------------------------------------------------------------
template<int CAUSAL>
__global__ __launch_bounds__(256)
void softmax_rows(float* __restrict__ scores)
{
  const int row  = blockIdx.x*4 + (threadIdx.x >> 6);
  const int lane = threadIdx.x & 63;
  const int q = row & 511;
  const float* srow = scores + (size_t)row*512;
  float s[8]; float m = -1e30f;
  #pragma unroll
  for (int i = 0; i < 8; i++){
    const int col = lane*8 + i;
    float v = srow[col] * 0.044194173824159216f;   // 1/sqrt(512)
    if (CAUSAL && col > q) v = -1e30f;
    s[i] = v; m = fmaxf(m, v);
  }
  #pragma unroll
  for (int o = 32; o; o >>= 1) m = fmaxf(m, __shfl_xor(m, o));
  float p[8], sum = 0.f;
  #pragma unroll
  for (int i = 0; i < 8; i++){
    float e = __expf(s[i] - m);
    if (CAUSAL && (lane*8 + i) > q) e = 0.f;
    p[i] = e; sum += e;
  }
  #pragma unroll
  for (int o = 32; o; o >>= 1) sum += __shfl_xor(sum, o);
  const float inv = 1.0f / sum;
  unsigned short* prow = (unsigned short*)scores + (size_t)row*1024;
  #pragma unroll
  for (int i = 0; i < 8; i++) prow[lane*8 + i] = f2bf(p[i] * inv);
}

// ---------------------------------------------------------------------------
// y = LayerNorm(x + delta) * g + b ; writes f32 (and optionally bf16 copy).
// One wave per 512-elem row.
// ---------------------------------------------------------------------------
template<int WRITE_BF>
__global__ __launch_bounds__(64)
void ln_rows(const float* __restrict__ x, const float* __restrict__ dly,
             const float* __restrict__ g, const float* __restrict__ bta,
             float* __restrict__ xo, unsigned short* __restrict__ xb)
{
  const int row = blockIdx.x, lane = threadIdx.x;
  const float* xr = x   + (size_t)row*512;
  const float* dr = dly + (size_t)row*512;
  float v[8]; float sum = 0.f;
  #pragma unroll
  for (int i = 0; i < 8; i++){ v[i] = xr[lane*8 + i] + dr[lane*8 + i]; sum += v[i]; }
  #pragma unroll
  for (int o = 32; o; o >>= 1) sum += __shfl_xor(sum, o);
  const float mean = sum * (1.0f/512.0f);
  float s2 = 0.f;
  #pragma unroll
  for (int i = 0; i < 8; i++){ const float t = v[i] - mean; s2 += t*t; }
  #pragma unroll
  for (int o = 32; o; o >>= 1) s2 += __shfl_xor(s2, o);
  const float inv = rsqrtf(s2 * (1.0f/512.0f) + 1e-3f);
  #pragma unroll
  for (int i = 0; i < 8; i++){
    const int c = lane*8 + i;
    const float y = (v[i] - mean)*inv*g[c] + bta[c];
    xo[(size_t)row*512 + c] = y;
    if (WRITE_BF) xb[(size_t)row*512 + c] = f2bf(y);
  }
}

__global__ __launch_bounds__(256)
void cast_bf16_k(const float* __restrict__ s, unsigned short* __restrict__ d, int n)
{
  const int i = (blockIdx.x*256 + threadIdx.x)*4;
  if (i < n){
    const float4 v = *(const float4*)(s + i);
    uint2 o;
    o.x = (unsigned)f2bf(v.x) | ((unsigned)f2bf(v.y) << 16);
    o.y = (unsigned)f2bf(v.z) | ((unsigned)f2bf(v.w) << 16);
    *(uint2*)(d + i) = o;
  }
}

// src [R][C] f32 -> dst [C][R] bf16
__global__ __launch_bounds__(256)
void transpose_cast(const float* __restrict__ src, unsigned short* __restrict__ dst, int R, int C)
{
  __shared__ float tile[32][33];
  const int bx = blockIdx.x*32, by = blockIdx.y*32;
  const int tx = threadIdx.x, ty = threadIdx.y;
  #pragma unroll
  for (int i = 0; i < 32; i += 8) tile[ty + i][tx] = src[(size_t)(by + ty + i)*C + bx + tx];
  __syncthreads();
  #pragma unroll
  for (int i = 0; i < 32; i += 8) dst[(size_t)(bx + ty + i)*R + by + tx] = f2bf(tile[tx][ty + i]);
}

// ---------------------------------------------------------------------------
extern "C" void kernel_launch(void* const* d_in, const int* in_sizes, int n_in,
                              void* d_out, int out_size, void* d_ws, size_t ws_size,
                              hipStream_t stream)
{
  (void)in_sizes; (void)n_in; (void)out_size; (void)ws_size;

  const float* in_seq  = (const float*)d_in[0];
  const float* out_seq = (const float*)d_in[1];
  const float* sa_wq = (const float*)d_in[2];  const float* sa_bq = (const float*)d_in[3];
  const float* sa_wk = (const float*)d_in[4];  const float* sa_bk = (const float*)d_in[5];
  const float* sa_wv = (const float*)d_in[6];  const float* sa_bv = (const float*)d_in[7];
  const float* sa_wo = (const float*)d_in[8];  const float* sa_bo = (const float*)d_in[9];
  const float* sa_lng = (const float*)d_in[10]; const float* sa_lnb = (const float*)d_in[11];
  const float* ca_wq = (const float*)d_in[12]; const float* ca_bq = (const float*)d_in[13];
  const float* ca_wk = (const float*)d_in[14]; const float* ca_bk = (const float*)d_in[15];
  const float* ca_wv = (const float*)d_in[16]; const float* ca_bv = (const float*)d_in[17];
  const float* ca_wo = (const float*)d_in[18]; const float* ca_bo = (const float*)d_in[19];
  const float* ca_lng = (const float*)d_in[20]; const float* ca_lnb = (const float*)d_in[21];
  const float* ff_w1 = (const float*)d_in[22]; const float* ff_b1 = (const float*)d_in[23];
  const float* ff_w2 = (const float*)d_in[24]; const float* ff_b2 = (const float*)d_in[25];
  const float* ff_lng = (const float*)d_in[26]; const float* ff_lnb = (const float*)d_in[27];

  char* ws = (char*)d_ws;
  size_t off = 0;
  auto alloc = [&](size_t bytes){ char* p = ws + off; off += (bytes + 255) & ~(size_t)255; return p; };

  unsigned short* wT[8];
  for (int i = 0; i < 8; i++) wT[i] = (unsigned short*)alloc(4096ULL*512*2);
  unsigned short* w1T  = (unsigned short*)alloc(1024ULL*512*2);
  unsigned short* w2T  = (unsigned short*)alloc(512ULL*1024*2);
  unsigned short* xbf  = (unsigned short*)alloc(4096ULL*512*2);
  unsigned short* inbf = (unsigned short*)alloc(4096ULL*512*2);
  unsigned short* qb   = (unsigned short*)alloc(4096ULL*4096*2);   // also FFN hidden
  unsigned short* kb   = (unsigned short*)alloc(4096ULL*4096*2);   // also attn-out
  unsigned short* vT   = (unsigned short*)alloc(64ULL*512*512*2);
  float*          sc   = (float*)alloc(64ULL*512*512*4);           // scores (+in-place probs)
  float*          tmp  = (float*)alloc(4096ULL*512*4);
  float*          xcur = (float*)alloc(4096ULL*512*4);

  dim3 tb(32, 8);
  cast_bf16_k<<<2048, 256, 0, stream>>>(out_seq, xbf, 4096*512);
  cast_bf16_k<<<2048, 256, 0, stream>>>(in_seq, inbf, 4096*512);
  // weights -> [N][K] bf16
  transpose_cast<<<dim3(128,16), tb, 0, stream>>>(sa_wq, wT[0], 512, 4096);
  transpose_cast<<<dim3(128,16), tb, 0, stream>>>(sa_wk, wT[1], 512, 4096);
  transpose_cast<<<dim3(128,16), tb, 0, stream>>>(sa_wv, wT[2], 512, 4096);
  transpose_cast<<<dim3(16,128), tb, 0, stream>>>(sa_wo, wT[3], 4096, 512);
  transpose_cast<<<dim3(128,16), tb, 0, stream>>>(ca_wq, wT[4], 512, 4096);
  transpose_cast<<<dim3(128,16), tb, 0, stream>>>(ca_wk, wT[5], 512, 4096);
  transpose_cast<<<dim3(128,16), tb, 0, stream>>>(ca_wv, wT[6], 512, 4096);
  transpose_cast<<<dim3(16,128), tb, 0, stream>>>(ca_wo, wT[7], 4096, 512);
  transpose_cast<<<dim3(32,16),  tb, 0, stream>>>(ff_w1, w1T, 512, 1024);
  transpose_cast<<<dim3(16,32),  tb, 0, stream>>>(ff_w2, w2T, 1024, 512);

  #define GEMM(MODE, Apt, Bpt, Cpt, BIAS, M, N, K, LDA, LDB, LDC, Z, aH, aB, bH, bB, cH, cB) \
    gemm_bt<MODE><<<dim3((N)/128,(M)/128,(Z)), 256, 0, stream>>>( \
      (const unsigned short*)(Apt), (const unsigned short*)(Bpt), (void*)(Cpt), BIAS, \
      M, N, K, LDA, LDB, LDC, aH, aB, bH, bB, cH, cB)

  // ---- self-attention (causal) ----
  GEMM(1, xbf, wT[0], qb, sa_bq, 4096, 4096, 512, 512, 512, 4096, 1, 0,0,0,0,0,0);
  GEMM(1, xbf, wT[1], kb, sa_bk, 4096, 4096, 512, 512, 512, 4096, 1, 0,0,0,0,0,0);
  GEMM(3, xbf, wT[2], vT, sa_bv, 4096, 4096, 512, 512, 512, 0,    1, 0,0,0,0,0,0);
  GEMM(0, qb, kb, sc, nullptr, 512, 512, 512, 4096, 4096, 512, 64,
       512, 2097152, 512, 2097152, 262144, 2097152);
  softmax_rows<1><<<8192, 256, 0, stream>>>(sc);
  GEMM(1, sc, vT, kb, nullptr, 512, 512, 512, 1024, 512, 4096, 64,
       524288, 4194304, 262144, 2097152, 512, 2097152);
  GEMM(0, kb, wT[3], tmp, sa_bo, 4096, 512, 4096, 4096, 4096, 512, 1, 0,0,0,0,0,0);
  ln_rows<1><<<4096, 64, 0, stream>>>(out_seq, tmp, sa_lng, sa_lnb, xcur, xbf);

  // ---- cross-attention ----
  GEMM(1, xbf,  wT[4], qb, ca_bq, 4096, 4096, 512, 512, 512, 4096, 1, 0,0,0,0,0,0);
  GEMM(1, inbf, wT[5], kb, ca_bk, 4096, 4096, 512, 512, 512, 4096, 1, 0,0,0,0,0,0);
  GEMM(3, inbf, wT[6], vT, ca_bv, 4096, 4096, 512, 512, 512, 0,    1, 0,0,0,0,0,0);
  GEMM(0, qb, kb, sc, nullptr, 512, 512, 512, 4096, 4096, 512, 64,
       512, 2097152, 512, 2097152, 262144, 2097152);
  softmax_rows<0><<<8192, 256, 0, stream>>>(sc);
  GEMM(1, sc, vT, kb, nullptr, 512, 512, 512, 1024, 512, 4096, 64,
       524288, 4194304, 262144, 2097152, 512, 2097152);
  GEMM(0, kb, wT[7], tmp, ca_bo, 4096, 512, 4096, 4096, 4096, 512, 1, 0,0,0,0,0,0);
  ln_rows<1><<<4096, 64, 0, stream>>>(xcur, tmp, ca_lng, ca_lnb, xcur, xbf);

  // ---- FFN ----
  GEMM(2, xbf, w1T, qb, ff_b1, 4096, 1024, 512, 512, 512, 1024, 1, 0,0,0,0,0,0);
  GEMM(0, qb, w2T, tmp, ff_b2, 4096, 512, 1024, 1024, 1024, 512, 1, 0,0,0,0,0,0);
  ln_rows<0><<<4096, 64, 0, stream>>>(xcur, tmp, ff_lng, ff_lnb, (float*)d_out, nullptr);

  #undef GEMM
}

// Round 3
// 618.437 us; speedup vs baseline: 1.0686x; 1.0686x over previous
//
#include <hip/hip_runtime.h>
#include <math.h>

#define DEV __device__ __forceinline__

typedef __bf16 bf16x8 __attribute__((ext_vector_type(8)));
typedef float f32x4 __attribute__((ext_vector_type(4)));

typedef const __attribute__((address_space(1))) void gv_t;
typedef __attribute__((address_space(3))) void lv_t;

DEV unsigned short f2bf(float f){
  unsigned int u = __float_as_uint(f);
  u += 0x7fffu + ((u >> 16) & 1u);     // round-to-nearest-even
  return (unsigned short)(u >> 16);
}

DEV void gload16(const void* g, void* l){
  __builtin_amdgcn_global_load_lds((gv_t*)g, (lv_t*)l, 16, 0, 0);
}

// ---------------------------------------------------------------------------
// C[M,N] = A[M,K] (bf16, row-major, lda) * B^T  (B given as [N][K] bf16, ldb)
// CMODE: 0 = f32 store (+bias), 1 = bf16 store (+bias), 2 = bf16 gelu(+bias)
// CSK:   0 = none, 1 = causal block-skip (scores: skip n0 > m0+127),
//        2 = causal K-clamp (PV: Keff = m0+128)
// Batched over blockIdx.z: z = b*8+h, operand offsets in ELEMENTS.
// K tile-count (Keff/32) must be EVEN. Dims multiples of 128/32.
// 2-phase double-buffered pipeline: stage(t+1) issued before compute(t),
// single barrier per K-step (T3-minimum recipe).
// ---------------------------------------------------------------------------
template<int CMODE, int CSK>
__global__ __launch_bounds__(256, 2)
void gemm_bt(const unsigned short* __restrict__ A, const unsigned short* __restrict__ B,
             void* __restrict__ C, const float* __restrict__ bias,
             int M, int N, int K, int lda, int ldb, int ldc,
             size_t aOffH, size_t aOffB, size_t bOffH, size_t bOffB,
             size_t cOffH, size_t cOffB)
{
  __shared__ unsigned short At0[128*32];
  __shared__ unsigned short Bt0[128*32];
  __shared__ unsigned short At1[128*32];
  __shared__ unsigned short Bt1[128*32];

  const int m0 = blockIdx.y*128, n0 = blockIdx.x*128;
  if (CSK == 1 && n0 > m0 + 127) return;   // fully-masked causal block

  const int z = blockIdx.z, bb = z >> 3, hh = z & 7;
  A += (size_t)bb*aOffB + (size_t)hh*aOffH;
  B += (size_t)bb*bOffB + (size_t)hh*bOffH;
  const size_t coff = (size_t)bb*cOffB + (size_t)hh*cOffH;

  const int tid = threadIdx.x, w = tid >> 6, lane = tid & 63;
  const int wr = w >> 1, wc = w & 1;

  int Keff = K;
  if (CSK == 2) Keff = (m0 + 128 < K) ? (m0 + 128) : K;
  const int nt = Keff >> 5;                // even by construction

  f32x4 acc[4][4] = {};

  const int srow = lane >> 2;              // row within 16-row chunk
  const int scol = (lane & 3) * 8;         // element offset within 32-elem row

  auto stage = [&](unsigned short* AT, unsigned short* BT, int kt){
    #pragma unroll
    for (int j = 0; j < 2; j++){
      const int c = w*2 + j;               // chunk 0..7 (16 rows each)
      const int r = c*16 + srow;
      gload16(A + (size_t)(m0 + r)*lda + kt + scol, AT + c*512);
      gload16(B + (size_t)(n0 + r)*ldb + kt + scol, BT + c*512);
    }
  };
  auto compute = [&](const unsigned short* AT, const unsigned short* BT){
    bf16x8 af[4], bfr[4];
    const int kq = (lane >> 4) * 8;
    #pragma unroll
    for (int i = 0; i < 4; i++){
      af[i]  = *(const bf16x8*)&AT[(wr*64 + i*16 + (lane & 15))*32 + kq];
      bfr[i] = *(const bf16x8*)&BT[(wc*64 + i*16 + (lane & 15))*32 + kq];
    }
    #pragma unroll
    for (int i = 0; i < 4; i++)
      #pragma unroll
      for (int jj = 0; jj < 4; jj++)
        acc[i][jj] = __builtin_amdgcn_mfma_f32_16x16x32_bf16(af[i], bfr[jj], acc[i][jj], 0, 0, 0);
  };

  stage(At0, Bt0, 0);
  __syncthreads();                          // drains vmcnt -> tile 0 resident
  for (int t = 0; t < nt; t += 2){
    stage(At1, Bt1, (t+1)*32);              // issue next while computing cur
    compute(At0, Bt0);
    __syncthreads();                        // waits stage(t+1); protects At0 reuse
    if (t+2 < nt) stage(At0, Bt0, (t+2)*32);
    compute(At1, Bt1);
    __syncthreads();
  }

  // Epilogue. C/D frag layout: col = lane&15, row = (lane>>4)*4 + reg.
  #pragma unroll
  for (int i = 0; i < 4; i++){
    const int mbase = m0 + wr*64 + i*16 + ((lane >> 4) << 2);
    #pragma unroll
    for (int jj = 0; jj < 4; jj++){
      const int n = n0 + wc*64 + jj*16 + (lane & 15);
      const float bv = bias ? bias[n] : 0.0f;
      #pragma unroll
      for (int r = 0; r < 4; r++){
        const int m = mbase + r;
        float v = acc[i][jj][r] + bv;
        if (CMODE == 0){
          ((float*)C)[coff + (size_t)m*ldc + n] = v;
        } else if (CMODE == 1){
          ((unsigned short*)C)[coff + (size_t)m*ldc + n] = f2bf(v);
        } else {
          v = 0.5f * v * (1.0f + erff(v * 0.70710678118654752f));   // exact GELU
          ((unsigned short*)C)[coff + (size_t)m*ldc + n] = f2bf(v);
        }
      }
    }
  }
}

// ---------------------------------------------------------------------------
// Row softmax over scores [64][512][512] f32, in-place; writes bf16 probs into
// the first 1024 bytes of each 2048-byte row (so probs lda = 1024 ushorts).
// One wave per row; scale = 1/sqrt(512) applied here.
// ---------------------------------------------------------------------------
template<int CAUSAL>
__global__ __launch_bounds__(256)
void softmax_rows(float* __restrict__ scores)
{
  const int row  = blockIdx.x*4 + (threadIdx.x >> 6);
  const int lane = threadIdx.x & 63;
  const int q = row & 511;
  const float* srow = scores + (size_t)row*512;
  float s[8]; float m = -1e30f;
  #pragma unroll
  for (int i = 0; i < 8; i++){
    const int col = lane*8 + i;
    float v = srow[col] * 0.044194173824159216f;   // 1/sqrt(512)
    if (CAUSAL && col > q) v = -1e30f;
    s[i] = v; m = fmaxf(m, v);
  }
  #pragma unroll
  for (int o = 32; o; o >>= 1) m = fmaxf(m, __shfl_xor(m, o));
  float p[8], sum = 0.f;
  #pragma unroll
  for (int i = 0; i < 8; i++){
    float e = __expf(s[i] - m);
    if (CAUSAL && (lane*8 + i) > q) e = 0.f;
    p[i] = e; sum += e;
  }
  #pragma unroll
  for (int o = 32; o; o >>= 1) sum += __shfl_xor(sum, o);
  const float inv = 1.0f / sum;
  unsigned short* prow = (unsigned short*)scores + (size_t)row*1024;
  #pragma unroll
  for (int i = 0; i < 8; i++) prow[lane*8 + i] = f2bf(p[i] * inv);
}

// ---------------------------------------------------------------------------
// y = LayerNorm(x + d1 [+ d2] [+ bias]) * g + b ; writes f32 (+optional bf16).
// 4 rows per 256-thread block, one wave per 512-elem row.
// ---------------------------------------------------------------------------
template<int WRITE_BF>
__global__ __launch_bounds__(256)
void ln_rows(const float* __restrict__ x, const float* __restrict__ d1,
             const float* __restrict__ d2, const float* __restrict__ bias,
             const float* __restrict__ g, const float* __restrict__ bta,
             float* __restrict__ xo, unsigned short* __restrict__ xb)
{
  const int row = blockIdx.x*4 + (threadIdx.x >> 6);
  const int lane = threadIdx.x & 63;
  const float* xr = x  + (size_t)row*512;
  const float* d1r = d1 + (size_t)row*512;
  const float* d2r = d2 ? d2 + (size_t)row*512 : nullptr;
  float v[8]; float sum = 0.f;
  #pragma unroll
  for (int i = 0; i < 8; i++){
    const int c = lane*8 + i;
    float t = xr[c] + d1r[c];
    if (d2) t += d2r[c];
    if (bias) t += bias[c];
    v[i] = t; sum += t;
  }
  #pragma unroll
  for (int o = 32; o; o >>= 1) sum += __shfl_xor(sum, o);
  const float mean = sum * (1.0f/512.0f);
  float s2 = 0.f;
  #pragma unroll
  for (int i = 0; i < 8; i++){ const float t = v[i] - mean; s2 += t*t; }
  #pragma unroll
  for (int o = 32; o; o >>= 1) s2 += __shfl_xor(s2, o);
  const float inv = rsqrtf(s2 * (1.0f/512.0f) + 1e-3f);
  #pragma unroll
  for (int i = 0; i < 8; i++){
    const int c = lane*8 + i;
    const float y = (v[i] - mean)*inv*g[c] + bta[c];
    xo[(size_t)row*512 + c] = y;
    if (WRITE_BF) xb[(size_t)row*512 + c] = f2bf(y);
  }
}

__global__ __launch_bounds__(256)
void cast_bf16_k(const float* __restrict__ s, unsigned short* __restrict__ d, int n)
{
  const int i = (blockIdx.x*256 + threadIdx.x)*4;
  if (i < n){
    const float4 v = *(const float4*)(s + i);
    uint2 o;
    o.x = (unsigned)f2bf(v.x) | ((unsigned)f2bf(v.y) << 16);
    o.y = (unsigned)f2bf(v.z) | ((unsigned)f2bf(v.w) << 16);
    *(uint2*)(d + i) = o;
  }
}

// src [R][C] f32 -> dst [C][R] bf16
__global__ __launch_bounds__(256)
void transpose_cast(const float* __restrict__ src, unsigned short* __restrict__ dst, int R, int C)
{
  __shared__ float tile[32][33];
  const int bx = blockIdx.x*32, by = blockIdx.y*32;
  const int tx = threadIdx.x, ty = threadIdx.y;
  #pragma unroll
  for (int i = 0; i < 32; i += 8) tile[ty + i][tx] = src[(size_t)(by + ty + i)*C + bx + tx];
  __syncthreads();
  #pragma unroll
  for (int i = 0; i < 32; i += 8) dst[(size_t)(bx + ty + i)*R + by + tx] = f2bf(tile[tx][ty + i]);
}

// vb [4096 m=(b,s)][4096 n=(h,ko)] bf16  ->  vT [b][h][ko][s] bf16
__global__ __launch_bounds__(256)
void transpose_v(const unsigned short* __restrict__ src, unsigned short* __restrict__ dst)
{
  __shared__ unsigned short t[32][34];
  const int z = blockIdx.z, b = z >> 3, h = z & 7;
  const int s0 = blockIdx.y*32, k0 = blockIdx.x*32;
  const int tx = threadIdx.x & 31, ty4 = (threadIdx.x >> 5) * 4;
  #pragma unroll
  for (int i = 0; i < 4; i++)
    t[ty4 + i][tx] = src[(size_t)(b*512 + s0 + ty4 + i)*4096 + h*512 + k0 + tx];
  __syncthreads();
  unsigned short* d = dst + ((size_t)z*512 + k0)*512 + s0;
  #pragma unroll
  for (int i = 0; i < 4; i++)
    d[(size_t)(ty4 + i)*512 + tx] = t[tx][ty4 + i];
}

// ---------------------------------------------------------------------------
extern "C" void kernel_launch(void* const* d_in, const int* in_sizes, int n_in,
                              void* d_out, int out_size, void* d_ws, size_t ws_size,
                              hipStream_t stream)
{
  (void)in_sizes; (void)n_in; (void)out_size; (void)ws_size;

  const float* in_seq  = (const float*)d_in[0];
  const float* out_seq = (const float*)d_in[1];
  const float* sa_wq = (const float*)d_in[2];  const float* sa_bq = (const float*)d_in[3];
  const float* sa_wk = (const float*)d_in[4];  const float* sa_bk = (const float*)d_in[5];
  const float* sa_wv = (const float*)d_in[6];  const float* sa_bv = (const float*)d_in[7];
  const float* sa_wo = (const float*)d_in[8];  const float* sa_bo = (const float*)d_in[9];
  const float* sa_lng = (const float*)d_in[10]; const float* sa_lnb = (const float*)d_in[11];
  const float* ca_wq = (const float*)d_in[12]; const float* ca_bq = (const float*)d_in[13];
  const float* ca_wk = (const float*)d_in[14]; const float* ca_bk = (const float*)d_in[15];
  const float* ca_wv = (const float*)d_in[16]; const float* ca_bv = (const float*)d_in[17];
  const float* ca_wo = (const float*)d_in[18]; const float* ca_bo = (const float*)d_in[19];
  const float* ca_lng = (const float*)d_in[20]; const float* ca_lnb = (const float*)d_in[21];
  const float* ff_w1 = (const float*)d_in[22]; const float* ff_b1 = (const float*)d_in[23];
  const float* ff_w2 = (const float*)d_in[24]; const float* ff_b2 = (const float*)d_in[25];
  const float* ff_lng = (const float*)d_in[26]; const float* ff_lnb = (const float*)d_in[27];

  char* ws = (char*)d_ws;
  size_t off = 0;
  auto alloc = [&](size_t bytes){ char* p = ws + off; off += (bytes + 255) & ~(size_t)255; return p; };

  unsigned short* wT[8];
  for (int i = 0; i < 8; i++) wT[i] = (unsigned short*)alloc(4096ULL*512*2);
  unsigned short* w1T  = (unsigned short*)alloc(1024ULL*512*2);
  unsigned short* w2T  = (unsigned short*)alloc(512ULL*1024*2);
  unsigned short* xbf  = (unsigned short*)alloc(4096ULL*512*2);
  unsigned short* inbf = (unsigned short*)alloc(4096ULL*512*2);
  unsigned short* qb   = (unsigned short*)alloc(4096ULL*4096*2);   // also FFN hidden
  unsigned short* kb   = (unsigned short*)alloc(4096ULL*4096*2);   // also attn-out
  unsigned short* vT   = (unsigned short*)alloc(64ULL*512*512*2);
  float*          sc   = (float*)alloc(64ULL*512*512*4);           // scores (+probs)
  float*          tmp  = (float*)alloc(4096ULL*512*4);
  float*          xcur = (float*)alloc(4096ULL*512*4);

  // Aliased into the (temporally dead) scores region.  NOTE (R2 bug): sc holds
  // 16M floats, so sc+16M was exactly `tmp` — split-K halves raced.  tmp2 now
  // sits at the START of sc, which is dead at every out-proj/ff2 (vb and probs
  // are both fully consumed before those GEMMs run).
  unsigned short* vb   = (unsigned short*)sc;          // dead before scores GEMM
  float*          tmp2 = (float*)sc;                   // split-K partial (8 MiB)

  dim3 tb(32, 8);
  cast_bf16_k<<<2048, 256, 0, stream>>>(out_seq, xbf, 4096*512);
  cast_bf16_k<<<2048, 256, 0, stream>>>(in_seq, inbf, 4096*512);
  // weights -> [N][K] bf16
  transpose_cast<<<dim3(128,16), tb, 0, stream>>>(sa_wq, wT[0], 512, 4096);
  transpose_cast<<<dim3(128,16), tb, 0, stream>>>(sa_wk, wT[1], 512, 4096);
  transpose_cast<<<dim3(128,16), tb, 0, stream>>>(sa_wv, wT[2], 512, 4096);
  transpose_cast<<<dim3(16,128), tb, 0, stream>>>(sa_wo, wT[3], 4096, 512);
  transpose_cast<<<dim3(128,16), tb, 0, stream>>>(ca_wq, wT[4], 512, 4096);
  transpose_cast<<<dim3(128,16), tb, 0, stream>>>(ca_wk, wT[5], 512, 4096);
  transpose_cast<<<dim3(128,16), tb, 0, stream>>>(ca_wv, wT[6], 512, 4096);
  transpose_cast<<<dim3(16,128), tb, 0, stream>>>(ca_wo, wT[7], 4096, 512);
  transpose_cast<<<dim3(32,16),  tb, 0, stream>>>(ff_w1, w1T, 512, 1024);
  transpose_cast<<<dim3(16,32),  tb, 0, stream>>>(ff_w2, w2T, 1024, 512);

  #define GEMM(MODE, CSK, Apt, Bpt, Cpt, BIAS, M, N, K, LDA, LDB, LDC, Z, aH, aB, bH, bB, cH, cB) \
    gemm_bt<MODE, CSK><<<dim3((N)/128,(M)/128,(Z)), 256, 0, stream>>>( \
      (const unsigned short*)(Apt), (const unsigned short*)(Bpt), (void*)(Cpt), BIAS, \
      M, N, K, LDA, LDB, LDC, aH, aB, bH, bB, cH, cB)

  // ---- self-attention (causal) ----
  GEMM(1, 0, xbf, wT[0], qb, sa_bq, 4096, 4096, 512, 512, 512, 4096, 1, 0,0,0,0,0,0);
  GEMM(1, 0, xbf, wT[1], kb, sa_bk, 4096, 4096, 512, 512, 512, 4096, 1, 0,0,0,0,0,0);
  GEMM(1, 0, xbf, wT[2], vb, sa_bv, 4096, 4096, 512, 512, 512, 4096, 1, 0,0,0,0,0,0);
  transpose_v<<<dim3(16,16,64), 256, 0, stream>>>(vb, vT);
  GEMM(0, 1, qb, kb, sc, nullptr, 512, 512, 512, 4096, 4096, 512, 64,
       512, 2097152, 512, 2097152, 262144, 2097152);
  softmax_rows<1><<<8192, 256, 0, stream>>>(sc);
  GEMM(1, 2, sc, vT, kb, nullptr, 512, 512, 512, 1024, 512, 4096, 64,
       524288, 4194304, 262144, 2097152, 512, 2097152);
  // out-proj, split-K=2 (z = k-split; col offsets via aH/bH, partials via cH)
  GEMM(0, 0, kb, wT[3], tmp, nullptr, 4096, 512, 2048, 4096, 4096, 512, 2,
       2048, 0, 2048, 0, (size_t)(tmp2 - tmp), 0);
  ln_rows<1><<<1024, 256, 0, stream>>>(out_seq, tmp, tmp2, sa_bo, sa_lng, sa_lnb, xcur, xbf);

  // ---- cross-attention ----
  GEMM(1, 0, xbf,  wT[4], qb, ca_bq, 4096, 4096, 512, 512, 512, 4096, 1, 0,0,0,0,0,0);
  GEMM(1, 0, inbf, wT[5], kb, ca_bk, 4096, 4096, 512, 512, 512, 4096, 1, 0,0,0,0,0,0);
  GEMM(1, 0, inbf, wT[6], vb, ca_bv, 4096, 4096, 512, 512, 512, 4096, 1, 0,0,0,0,0,0);
  transpose_v<<<dim3(16,16,64), 256, 0, stream>>>(vb, vT);
  GEMM(0, 0, qb, kb, sc, nullptr, 512, 512, 512, 4096, 4096, 512, 64,
       512, 2097152, 512, 2097152, 262144, 2097152);
  softmax_rows<0><<<8192, 256, 0, stream>>>(sc);
  GEMM(1, 0, sc, vT, kb, nullptr, 512, 512, 512, 1024, 512, 4096, 64,
       524288, 4194304, 262144, 2097152, 512, 2097152);
  GEMM(0, 0, kb, wT[7], tmp, nullptr, 4096, 512, 2048, 4096, 4096, 512, 2,
       2048, 0, 2048, 0, (size_t)(tmp2 - tmp), 0);
  ln_rows<1><<<1024, 256, 0, stream>>>(xcur, tmp, tmp2, ca_bo, ca_lng, ca_lnb, xcur, xbf);

  // ---- FFN ----
  GEMM(2, 0, xbf, w1T, qb, ff_b1, 4096, 1024, 512, 512, 512, 1024, 1, 0,0,0,0,0,0);
  GEMM(0, 0, qb, w2T, tmp, nullptr, 4096, 512, 512, 1024, 1024, 512, 2,
       512, 0, 512, 0, (size_t)(tmp2 - tmp), 0);
  ln_rows<0><<<1024, 256, 0, stream>>>(xcur, tmp, tmp2, ff_b2, ff_lng, ff_lnb, (float*)d_out, nullptr);

  #undef GEMM
}

// Round 4
// 616.237 us; speedup vs baseline: 1.0724x; 1.0036x over previous
//
#include <hip/hip_runtime.h>
#include <math.h>

#define DEV __device__ __forceinline__

typedef __bf16 bf16x8 __attribute__((ext_vector_type(8)));
typedef float f32x4 __attribute__((ext_vector_type(4)));

typedef const __attribute__((address_space(1))) void gv_t;
typedef __attribute__((address_space(3))) void lv_t;

DEV unsigned short f2bf(float f){
  unsigned int u = __float_as_uint(f);
  u += 0x7fffu + ((u >> 16) & 1u);     // round-to-nearest-even
  return (unsigned short)(u >> 16);
}

DEV void gload16(const void* g, void* l){
  __builtin_amdgcn_global_load_lds((gv_t*)g, (lv_t*)l, 16, 0, 0);
}

// ---------------------------------------------------------------------------
// gemm8: 256x256 tile, BK=64, 8 waves (2Mx4N), T3+T4 counted-vmcnt schedule,
// T2 XOR-swizzled LDS (elem col ^= (row&7)*8; applied to BOTH the pre-swizzled
// global source of global_load_lds (linear dest) and the ds_read address).
// C[M,N] = A[M,K]*B^T + bias, bf16 in, bf16 out. M,N mult of 256; K mult of
// 64, K>=128.
// ---------------------------------------------------------------------------
__global__ __launch_bounds__(512, 2)
void gemm8(const unsigned short* __restrict__ A, const unsigned short* __restrict__ B,
           unsigned short* __restrict__ C, const float* __restrict__ bias,
           int M, int N, int K, int lda, int ldb, int ldc)
{
  __shared__ unsigned short Ab[2][16384];   // [buf][256 rows][64 k]
  __shared__ unsigned short Bb[2][16384];
  const int m0 = blockIdx.y*256, n0 = blockIdx.x*256;
  const int tid = threadIdx.x, lane = tid & 63, w = tid >> 6;
  const int wr = w >> 2, wc = w & 3;        // wave -> (2 row, 4 col) grid
  const int NT = K >> 6;

  const int r8  = tid >> 3;                 // staging row within 64-row chunk
  const int sc8 = ((tid & 7) ^ (r8 & 7)) * 8;   // pre-swizzled source column

  auto stageT = [&](int buf, int kt){
    #pragma unroll
    for (int j = 0; j < 4; j++){
      gload16(A + (size_t)(m0 + j*64 + r8)*lda + kt + sc8, &Ab[buf][j*4096 + tid*8]);
      gload16(B + (size_t)(n0 + j*64 + r8)*ldb + kt + sc8, &Bb[buf][j*4096 + tid*8]);
    }
  };

  f32x4 acc[8][4] = {};

  stageT(0, 0);
  stageT(1, 64);                            // 16 loads/thread outstanding

  const int l15 = lane & 15, l4 = lane >> 4;

  for (int t = 0; t < NT; t++){
    const int cur = t & 1;
    // tile t resident once <=8 of our loads remain (tile t+1's, staged earlier)
    if (t + 1 < NT) asm volatile("s_waitcnt vmcnt(8)" ::: "memory");
    else            asm volatile("s_waitcnt vmcnt(0)" ::: "memory");
    __builtin_amdgcn_s_barrier();
    __builtin_amdgcn_sched_barrier(0);

    // B fragments are tile-invariant for this wave: read once (8 x ds_read_b128)
    bf16x8 bfr[4][2];
    #pragma unroll
    for (int fc = 0; fc < 4; fc++){
      const int R = wc*64 + fc*16 + l15;
      #pragma unroll
      for (int kc = 0; kc < 2; kc++){
        const int cc = (kc*32 + l4*8) ^ ((R & 7) * 8);
        bfr[fc][kc] = *(const bf16x8*)&Bb[cur][R*64 + cc];
      }
    }

    #pragma unroll
    for (int q = 0; q < 4; q++){            // 4 phases: 2 fragrows x 4 fragcols x 2k
      bf16x8 ar[2][2];
      #pragma unroll
      for (int f = 0; f < 2; f++){
        const int R = wr*128 + (q*2 + f)*16 + l15;
        #pragma unroll
        for (int kc = 0; kc < 2; kc++){
          const int cc = (kc*32 + l4*8) ^ ((R & 7) * 8);
          ar[f][kc] = *(const bf16x8*)&Ab[cur][R*64 + cc];
        }
      }
      if (q == 3){
        // all frags of buf[cur] now requested; drain own LDS reads, sync,
        // then overwrite buf[cur] with tile t+2 (loads span the next barrier)
        asm volatile("s_waitcnt lgkmcnt(0)" ::: "memory");
        __builtin_amdgcn_s_barrier();
        __builtin_amdgcn_sched_barrier(0);
        if (t + 2 < NT) stageT(cur, (t+2)*64);
      }
      __builtin_amdgcn_s_setprio(1);
      #pragma unroll
      for (int f = 0; f < 2; f++)
        #pragma unroll
        for (int fc = 0; fc < 4; fc++)
          #pragma unroll
          for (int kc = 0; kc < 2; kc++)
            acc[q*2+f][fc] = __builtin_amdgcn_mfma_f32_16x16x32_bf16(
                ar[f][kc], bfr[fc][kc], acc[q*2+f][fc], 0, 0, 0);
      __builtin_amdgcn_s_setprio(0);
    }
  }

  // epilogue: C/D frag layout col = lane&15, row = (lane>>4)*4 + reg
  #pragma unroll
  for (int fr = 0; fr < 8; fr++){
    const int mb = m0 + wr*128 + fr*16 + l4*4;
    #pragma unroll
    for (int fc = 0; fc < 4; fc++){
      const int n = n0 + wc*64 + fc*16 + l15;
      const float bv = bias ? bias[n] : 0.0f;
      #pragma unroll
      for (int r = 0; r < 4; r++)
        C[(size_t)(mb + r)*ldc + n] = f2bf(acc[fr][fc][r] + bv);
    }
  }
}

// ---------------------------------------------------------------------------
// 128^2 2-phase dbuf GEMM (R3, verified) — still used for scores/PV/out-proj/FFN.
// CMODE: 0 = f32 store (+bias), 1 = bf16 store (+bias), 2 = bf16 gelu(+bias)
// CSK:   0 = none, 1 = causal block-skip, 2 = causal K-clamp
// ---------------------------------------------------------------------------
template<int CMODE, int CSK>
__global__ __launch_bounds__(256, 2)
void gemm_bt(const unsigned short* __restrict__ A, const unsigned short* __restrict__ B,
             void* __restrict__ C, const float* __restrict__ bias,
             int M, int N, int K, int lda, int ldb, int ldc,
             size_t aOffH, size_t aOffB, size_t bOffH, size_t bOffB,
             size_t cOffH, size_t cOffB)
{
  __shared__ unsigned short At0[128*32];
  __shared__ unsigned short Bt0[128*32];
  __shared__ unsigned short At1[128*32];
  __shared__ unsigned short Bt1[128*32];

  const int m0 = blockIdx.y*128, n0 = blockIdx.x*128;
  if (CSK == 1 && n0 > m0 + 127) return;   // fully-masked causal block

  const int z = blockIdx.z, bb = z >> 3, hh = z & 7;
  A += (size_t)bb*aOffB + (size_t)hh*aOffH;
  B += (size_t)bb*bOffB + (size_t)hh*bOffH;
  const size_t coff = (size_t)bb*cOffB + (size_t)hh*cOffH;

  const int tid = threadIdx.x, w = tid >> 6, lane = tid & 63;
  const int wr = w >> 1, wc = w & 1;

  int Keff = K;
  if (CSK == 2) Keff = (m0 + 128 < K) ? (m0 + 128) : K;
  const int nt = Keff >> 5;                // even by construction

  f32x4 acc[4][4] = {};

  const int srow = lane >> 2;
  const int scol = (lane & 3) * 8;

  auto stage = [&](unsigned short* AT, unsigned short* BT, int kt){
    #pragma unroll
    for (int j = 0; j < 2; j++){
      const int c = w*2 + j;
      const int r = c*16 + srow;
      gload16(A + (size_t)(m0 + r)*lda + kt + scol, AT + c*512);
      gload16(B + (size_t)(n0 + r)*ldb + kt + scol, BT + c*512);
    }
  };
  auto compute = [&](const unsigned short* AT, const unsigned short* BT){
    bf16x8 af[4], bfr[4];
    const int kq = (lane >> 4) * 8;
    #pragma unroll
    for (int i = 0; i < 4; i++){
      af[i]  = *(const bf16x8*)&AT[(wr*64 + i*16 + (lane & 15))*32 + kq];
      bfr[i] = *(const bf16x8*)&BT[(wc*64 + i*16 + (lane & 15))*32 + kq];
    }
    #pragma unroll
    for (int i = 0; i < 4; i++)
      #pragma unroll
      for (int jj = 0; jj < 4; jj++)
        acc[i][jj] = __builtin_amdgcn_mfma_f32_16x16x32_bf16(af[i], bfr[jj], acc[i][jj], 0, 0, 0);
  };

  stage(At0, Bt0, 0);
  __syncthreads();
  for (int t = 0; t < nt; t += 2){
    stage(At1, Bt1, (t+1)*32);
    compute(At0, Bt0);
    __syncthreads();
    if (t+2 < nt) stage(At0, Bt0, (t+2)*32);
    compute(At1, Bt1);
    __syncthreads();
  }

  #pragma unroll
  for (int i = 0; i < 4; i++){
    const int mbase = m0 + wr*64 + i*16 + ((lane >> 4) << 2);
    #pragma unroll
    for (int jj = 0; jj < 4; jj++){
      const int n = n0 + wc*64 + jj*16 + (lane & 15);
      const float bv = bias ? bias[n] : 0.0f;
      #pragma unroll
      for (int r = 0; r < 4; r++){
        const int m = mbase + r;
        float v = acc[i][jj][r] + bv;
        if (CMODE == 0){
          ((float*)C)[coff + (size_t)m*ldc + n] = v;
        } else if (CMODE == 1){
          ((unsigned short*)C)[coff + (size_t)m*ldc + n] = f2bf(v);
        } else {
          v = 0.5f * v * (1.0f + erff(v * 0.70710678118654752f));   // exact GELU
          ((unsigned short*)C)[coff + (size_t)m*ldc + n] = f2bf(v);
        }
      }
    }
  }
}

// ---------------------------------------------------------------------------
template<int CAUSAL>
__global__ __launch_bounds__(256)
void softmax_rows(float* __restrict__ scores)
{
  const int row  = blockIdx.x*4 + (threadIdx.x >> 6);
  const int lane = threadIdx.x & 63;
  const int q = row & 511;
  const float* srow = scores + (size_t)row*512;
  float s[8]; float m = -1e30f;
  #pragma unroll
  for (int i = 0; i < 8; i++){
    const int col = lane*8 + i;
    float v = srow[col] * 0.044194173824159216f;   // 1/sqrt(512)
    if (CAUSAL && col > q) v = -1e30f;
    s[i] = v; m = fmaxf(m, v);
  }
  #pragma unroll
  for (int o = 32; o; o >>= 1) m = fmaxf(m, __shfl_xor(m, o));
  float p[8], sum = 0.f;
  #pragma unroll
  for (int i = 0; i < 8; i++){
    float e = __expf(s[i] - m);
    if (CAUSAL && (lane*8 + i) > q) e = 0.f;
    p[i] = e; sum += e;
  }
  #pragma unroll
  for (int o = 32; o; o >>= 1) sum += __shfl_xor(sum, o);
  const float inv = 1.0f / sum;
  unsigned short* prow = (unsigned short*)scores + (size_t)row*1024;
  #pragma unroll
  for (int i = 0; i < 8; i++) prow[lane*8 + i] = f2bf(p[i] * inv);
}

// ---------------------------------------------------------------------------
template<int WRITE_BF>
__global__ __launch_bounds__(256)
void ln_rows(const float* __restrict__ x, const float* __restrict__ d1,
             const float* __restrict__ d2, const float* __restrict__ bias,
             const float* __restrict__ g, const float* __restrict__ bta,
             float* __restrict__ xo, unsigned short* __restrict__ xb)
{
  const int row = blockIdx.x*4 + (threadIdx.x >> 6);
  const int lane = threadIdx.x & 63;
  const float* xr = x  + (size_t)row*512;
  const float* d1r = d1 + (size_t)row*512;
  const float* d2r = d2 ? d2 + (size_t)row*512 : nullptr;
  float v[8]; float sum = 0.f;
  #pragma unroll
  for (int i = 0; i < 8; i++){
    const int c = lane*8 + i;
    float t = xr[c] + d1r[c];
    if (d2) t += d2r[c];
    if (bias) t += bias[c];
    v[i] = t; sum += t;
  }
  #pragma unroll
  for (int o = 32; o; o >>= 1) sum += __shfl_xor(sum, o);
  const float mean = sum * (1.0f/512.0f);
  float s2 = 0.f;
  #pragma unroll
  for (int i = 0; i < 8; i++){ const float t = v[i] - mean; s2 += t*t; }
  #pragma unroll
  for (int o = 32; o; o >>= 1) s2 += __shfl_xor(s2, o);
  const float inv = rsqrtf(s2 * (1.0f/512.0f) + 1e-3f);
  #pragma unroll
  for (int i = 0; i < 8; i++){
    const int c = lane*8 + i;
    const float y = (v[i] - mean)*inv*g[c] + bta[c];
    xo[(size_t)row*512 + c] = y;
    if (WRITE_BF) xb[(size_t)row*512 + c] = f2bf(y);
  }
}

__global__ __launch_bounds__(256)
void cast_bf16_k(const float* __restrict__ s, unsigned short* __restrict__ d, int n)
{
  const int i = (blockIdx.x*256 + threadIdx.x)*4;
  if (i < n){
    const float4 v = *(const float4*)(s + i);
    uint2 o;
    o.x = (unsigned)f2bf(v.x) | ((unsigned)f2bf(v.y) << 16);
    o.y = (unsigned)f2bf(v.z) | ((unsigned)f2bf(v.w) << 16);
    *(uint2*)(d + i) = o;
  }
}

// src [R][C] f32 -> dst [C][R] bf16
__global__ __launch_bounds__(256)
void transpose_cast(const float* __restrict__ src, unsigned short* __restrict__ dst, int R, int C)
{
  __shared__ float tile[32][33];
  const int bx = blockIdx.x*32, by = blockIdx.y*32;
  const int tx = threadIdx.x, ty = threadIdx.y;
  #pragma unroll
  for (int i = 0; i < 32; i += 8) tile[ty + i][tx] = src[(size_t)(by + ty + i)*C + bx + tx];
  __syncthreads();
  #pragma unroll
  for (int i = 0; i < 32; i += 8) dst[(size_t)(bx + ty + i)*R + by + tx] = f2bf(tile[tx][ty + i]);
}

// vb [4096 m=(b,s)][4096 n=(h,ko)] bf16  ->  vT [b][h][ko][s] bf16
__global__ __launch_bounds__(256)
void transpose_v(const unsigned short* __restrict__ src, unsigned short* __restrict__ dst)
{
  __shared__ unsigned short t[32][34];
  const int z = blockIdx.z, b = z >> 3, h = z & 7;
  const int s0 = blockIdx.y*32, k0 = blockIdx.x*32;
  const int tx = threadIdx.x & 31, ty4 = (threadIdx.x >> 5) * 4;
  #pragma unroll
  for (int i = 0; i < 4; i++)
    t[ty4 + i][tx] = src[(size_t)(b*512 + s0 + ty4 + i)*4096 + h*512 + k0 + tx];
  __syncthreads();
  unsigned short* d = dst + ((size_t)z*512 + k0)*512 + s0;
  #pragma unroll
  for (int i = 0; i < 4; i++)
    d[(size_t)(ty4 + i)*512 + tx] = t[tx][ty4 + i];
}

// ---------------------------------------------------------------------------
extern "C" void kernel_launch(void* const* d_in, const int* in_sizes, int n_in,
                              void* d_out, int out_size, void* d_ws, size_t ws_size,
                              hipStream_t stream)
{
  (void)in_sizes; (void)n_in; (void)out_size; (void)ws_size;

  const float* in_seq  = (const float*)d_in[0];
  const float* out_seq = (const float*)d_in[1];
  const float* sa_wq = (const float*)d_in[2];  const float* sa_bq = (const float*)d_in[3];
  const float* sa_wk = (const float*)d_in[4];  const float* sa_bk = (const float*)d_in[5];
  const float* sa_wv = (const float*)d_in[6];  const float* sa_bv = (const float*)d_in[7];
  const float* sa_wo = (const float*)d_in[8];  const float* sa_bo = (const float*)d_in[9];
  const float* sa_lng = (const float*)d_in[10]; const float* sa_lnb = (const float*)d_in[11];
  const float* ca_wq = (const float*)d_in[12]; const float* ca_bq = (const float*)d_in[13];
  const float* ca_wk = (const float*)d_in[14]; const float* ca_bk = (const float*)d_in[15];
  const float* ca_wv = (const float*)d_in[16]; const float* ca_bv = (const float*)d_in[17];
  const float* ca_wo = (const float*)d_in[18]; const float* ca_bo = (const float*)d_in[19];
  const float* ca_lng = (const float*)d_in[20]; const float* ca_lnb = (const float*)d_in[21];
  const float* ff_w1 = (const float*)d_in[22]; const float* ff_b1 = (const float*)d_in[23];
  const float* ff_w2 = (const float*)d_in[24]; const float* ff_b2 = (const float*)d_in[25];
  const float* ff_lng = (const float*)d_in[26]; const float* ff_lnb = (const float*)d_in[27];

  char* ws = (char*)d_ws;
  size_t off = 0;
  auto alloc = [&](size_t bytes){ char* p = ws + off; off += (bytes + 255) & ~(size_t)255; return p; };

  unsigned short* wT[8];
  for (int i = 0; i < 8; i++) wT[i] = (unsigned short*)alloc(4096ULL*512*2);
  unsigned short* w1T  = (unsigned short*)alloc(1024ULL*512*2);
  unsigned short* w2T  = (unsigned short*)alloc(512ULL*1024*2);
  unsigned short* xbf  = (unsigned short*)alloc(4096ULL*512*2);
  unsigned short* inbf = (unsigned short*)alloc(4096ULL*512*2);
  unsigned short* qb   = (unsigned short*)alloc(4096ULL*4096*2);   // also FFN hidden
  unsigned short* kb   = (unsigned short*)alloc(4096ULL*4096*2);   // also attn-out
  unsigned short* vT   = (unsigned short*)alloc(64ULL*512*512*2);
  float*          sc   = (float*)alloc(64ULL*512*512*4);           // scores (+probs)
  float*          tmp  = (float*)alloc(4096ULL*512*4);
  float*          xcur = (float*)alloc(4096ULL*512*4);

  // tmp2 at the START of sc (dead at every out-proj/ff2); vb also aliases sc.
  unsigned short* vb   = (unsigned short*)sc;
  float*          tmp2 = (float*)sc;

  dim3 tb(32, 8);
  cast_bf16_k<<<2048, 256, 0, stream>>>(out_seq, xbf, 4096*512);
  cast_bf16_k<<<2048, 256, 0, stream>>>(in_seq, inbf, 4096*512);
  // weights -> [N][K] bf16
  transpose_cast<<<dim3(128,16), tb, 0, stream>>>(sa_wq, wT[0], 512, 4096);
  transpose_cast<<<dim3(128,16), tb, 0, stream>>>(sa_wk, wT[1], 512, 4096);
  transpose_cast<<<dim3(128,16), tb, 0, stream>>>(sa_wv, wT[2], 512, 4096);
  transpose_cast<<<dim3(16,128), tb, 0, stream>>>(sa_wo, wT[3], 4096, 512);
  transpose_cast<<<dim3(128,16), tb, 0, stream>>>(ca_wq, wT[4], 512, 4096);
  transpose_cast<<<dim3(128,16), tb, 0, stream>>>(ca_wk, wT[5], 512, 4096);
  transpose_cast<<<dim3(128,16), tb, 0, stream>>>(ca_wv, wT[6], 512, 4096);
  transpose_cast<<<dim3(16,128), tb, 0, stream>>>(ca_wo, wT[7], 4096, 512);
  transpose_cast<<<dim3(32,16),  tb, 0, stream>>>(ff_w1, w1T, 512, 1024);
  transpose_cast<<<dim3(16,32),  tb, 0, stream>>>(ff_w2, w2T, 1024, 512);

  #define GEMM(MODE, CSK, Apt, Bpt, Cpt, BIAS, M, N, K, LDA, LDB, LDC, Z, aH, aB, bH, bB, cH, cB) \
    gemm_bt<MODE, CSK><<<dim3((N)/128,(M)/128,(Z)), 256, 0, stream>>>( \
      (const unsigned short*)(Apt), (const unsigned short*)(Bpt), (void*)(Cpt), BIAS, \
      M, N, K, LDA, LDB, LDC, aH, aB, bH, bB, cH, cB)

  #define GEMM8(Apt, Bpt, Cpt, BIAS, M, N, K, LDA, LDB, LDC) \
    gemm8<<<dim3((N)/256,(M)/256), 512, 0, stream>>>( \
      (const unsigned short*)(Apt), (const unsigned short*)(Bpt), \
      (unsigned short*)(Cpt), BIAS, M, N, K, LDA, LDB, LDC)

  // ---- self-attention (causal) ----
  GEMM8(xbf, wT[0], qb, sa_bq, 4096, 4096, 512, 512, 512, 4096);
  GEMM8(xbf, wT[1], kb, sa_bk, 4096, 4096, 512, 512, 512, 4096);
  GEMM8(xbf, wT[2], vb, sa_bv, 4096, 4096, 512, 512, 512, 4096);
  transpose_v<<<dim3(16,16,64), 256, 0, stream>>>(vb, vT);
  GEMM(0, 1, qb, kb, sc, nullptr, 512, 512, 512, 4096, 4096, 512, 64,
       512, 2097152, 512, 2097152, 262144, 2097152);
  softmax_rows<1><<<8192, 256, 0, stream>>>(sc);
  GEMM(1, 2, sc, vT, kb, nullptr, 512, 512, 512, 1024, 512, 4096, 64,
       524288, 4194304, 262144, 2097152, 512, 2097152);
  GEMM(0, 0, kb, wT[3], tmp, nullptr, 4096, 512, 2048, 4096, 4096, 512, 2,
       2048, 0, 2048, 0, (size_t)(tmp2 - tmp), 0);
  ln_rows<1><<<1024, 256, 0, stream>>>(out_seq, tmp, tmp2, sa_bo, sa_lng, sa_lnb, xcur, xbf);

  // ---- cross-attention ----
  GEMM8(xbf,  wT[4], qb, ca_bq, 4096, 4096, 512, 512, 512, 4096);
  GEMM8(inbf, wT[5], kb, ca_bk, 4096, 4096, 512, 512, 512, 4096);
  GEMM8(inbf, wT[6], vb, ca_bv, 4096, 4096, 512, 512, 512, 4096);
  transpose_v<<<dim3(16,16,64), 256, 0, stream>>>(vb, vT);
  GEMM(0, 0, qb, kb, sc, nullptr, 512, 512, 512, 4096, 4096, 512, 64,
       512, 2097152, 512, 2097152, 262144, 2097152);
  softmax_rows<0><<<8192, 256, 0, stream>>>(sc);
  GEMM(1, 0, sc, vT, kb, nullptr, 512, 512, 512, 1024, 512, 4096, 64,
       524288, 4194304, 262144, 2097152, 512, 2097152);
  GEMM(0, 0, kb, wT[7], tmp, nullptr, 4096, 512, 2048, 4096, 4096, 512, 2,
       2048, 0, 2048, 0, (size_t)(tmp2 - tmp), 0);
  ln_rows<1><<<1024, 256, 0, stream>>>(xcur, tmp, tmp2, ca_bo, ca_lng, ca_lnb, xcur, xbf);

  // ---- FFN ----
  GEMM(2, 0, xbf, w1T, qb, ff_b1, 4096, 1024, 512, 512, 512, 1024, 1, 0,0,0,0,0,0);
  GEMM(0, 0, qb, w2T, tmp, nullptr, 4096, 512, 512, 1024, 1024, 512, 2,
       512, 0, 512, 0, (size_t)(tmp2 - tmp), 0);
  ln_rows<0><<<1024, 256, 0, stream>>>(xcur, tmp, tmp2, ff_b2, ff_lng, ff_lnb, (float*)d_out, nullptr);

  #undef GEMM
  #undef GEMM8
}

// Round 5
// 558.089 us; speedup vs baseline: 1.1842x; 1.1042x over previous
//
#include <hip/hip_runtime.h>
#include <math.h>

#define DEV __device__ __forceinline__

typedef __bf16 bf16x8 __attribute__((ext_vector_type(8)));
typedef float f32x4 __attribute__((ext_vector_type(4)));

typedef const __attribute__((address_space(1))) void gv_t;
typedef __attribute__((address_space(3))) void lv_t;

DEV unsigned short f2bf(float f){
  unsigned int u = __float_as_uint(f);
  u += 0x7fffu + ((u >> 16) & 1u);     // round-to-nearest-even
  return (unsigned short)(u >> 16);
}

DEV void gload16(const void* g, void* l){
  __builtin_amdgcn_global_load_lds((gv_t*)g, (lv_t*)l, 16, 0, 0);
}

// ---------------------------------------------------------------------------
// gemm256: 256x256 tile, BK=64, 8 waves (2M x 4N), plain 2-phase double-buffer
// (m230-V0 structure: STAGE(t+1) -> ds_read/MFMA(t) -> one __syncthreads).
// 2-way XOR swizzle on LDS (k-group ^= row&7; same involution on the
// pre-swizzled global source and on the ds_read address; linear LDS dest for
// global_load_lds per rule #21).
// C[M,N] = A[M,K] * B^T (+bias). CMODE: 0=f32 store, 1=bf16 store.
// CSK: 0=none, 1=causal block-skip (skip n0 > m0+255), 2=causal K-clamp
// (Keff = min(m0+256, K)). Batched over blockIdx.z (z = b*8+h), offsets in
// elements. M,N mult 256; K (and Keff) mult 64.
// ---------------------------------------------------------------------------
template<int CMODE, int CSK>
__global__ __launch_bounds__(512, 2)
void gemm256(const unsigned short* __restrict__ A, const unsigned short* __restrict__ B,
             void* __restrict__ C, const float* __restrict__ bias,
             int M, int N, int K, int lda, int ldb, int ldc,
             size_t aOffH, size_t aOffB, size_t bOffH, size_t bOffB,
             size_t cOffH, size_t cOffB)
{
  __shared__ unsigned short Ab[2][16384];   // [buf][256 rows][64 k]
  __shared__ unsigned short Bb[2][16384];

  const int m0 = blockIdx.y*256, n0 = blockIdx.x*256;
  if (CSK == 1 && n0 > m0 + 255) return;    // fully-masked causal block

  const int z = blockIdx.z, bb = z >> 3, hh = z & 7;
  A += (size_t)bb*aOffB + (size_t)hh*aOffH;
  B += (size_t)bb*bOffB + (size_t)hh*bOffH;
  const size_t coff = (size_t)bb*cOffB + (size_t)hh*cOffH;

  const int tid = threadIdx.x, lane = tid & 63, w = tid >> 6;
  const int wr = w >> 2, wc = w & 3;        // wave -> (2 row, 4 col)
  const int l15 = lane & 15, l4 = lane >> 4;

  int Keff = K;
  if (CSK == 2) Keff = (m0 + 256 < K) ? (m0 + 256) : K;
  const int nt = Keff >> 6;

  const int r8  = tid >> 3;                 // staging row within 64-row chunk... (0..63)
  const int sc8 = ((tid & 7) ^ (r8 & 7)) * 8;   // pre-swizzled source column

  auto stage = [&](int buf, int kt){
    #pragma unroll
    for (int j = 0; j < 4; j++){
      gload16(A + (size_t)(m0 + j*64 + r8)*lda + kt + sc8, &Ab[buf][j*4096 + tid*8]);
      gload16(B + (size_t)(n0 + j*64 + r8)*ldb + kt + sc8, &Bb[buf][j*4096 + tid*8]);
    }
  };

  f32x4 acc[8][4] = {};

  stage(0, 0);
  __syncthreads();
  for (int t = 0; t < nt; t++){
    const int cur = t & 1;
    if (t + 1 < nt) stage(cur ^ 1, (t+1)*64);   // prefetch next tile first

    bf16x8 bfr[4][2];                           // B frags: once per tile
    #pragma unroll
    for (int fc = 0; fc < 4; fc++){
      const int R = wc*64 + fc*16 + l15;
      #pragma unroll
      for (int kc = 0; kc < 2; kc++){
        const int cc = (kc*32 + l4*8) ^ ((R & 7) * 8);
        bfr[fc][kc] = *(const bf16x8*)&Bb[cur][R*64 + cc];
      }
    }
    #pragma unroll
    for (int fr = 0; fr < 8; fr++){
      bf16x8 ar[2];
      const int R = wr*128 + fr*16 + l15;
      #pragma unroll
      for (int kc = 0; kc < 2; kc++){
        const int cc = (kc*32 + l4*8) ^ ((R & 7) * 8);
        ar[kc] = *(const bf16x8*)&Ab[cur][R*64 + cc];
      }
      #pragma unroll
      for (int fc = 0; fc < 4; fc++)
        #pragma unroll
        for (int kc = 0; kc < 2; kc++)
          acc[fr][fc] = __builtin_amdgcn_mfma_f32_16x16x32_bf16(
              ar[kc], bfr[fc][kc], acc[fr][fc], 0, 0, 0);
    }
    __syncthreads();                            // drains stage(t+1) + frees buf
  }

  // epilogue: C/D frag layout col = lane&15, row = (lane>>4)*4 + reg
  #pragma unroll
  for (int fr = 0; fr < 8; fr++){
    const int mb = m0 + wr*128 + fr*16 + l4*4;
    #pragma unroll
    for (int fc = 0; fc < 4; fc++){
      const int n = n0 + wc*64 + fc*16 + l15;
      const float bv = bias ? bias[n] : 0.0f;
      #pragma unroll
      for (int r = 0; r < 4; r++){
        const float v = acc[fr][fc][r] + bv;
        if (CMODE == 0) ((float*)C)[coff + (size_t)(mb + r)*ldc + n] = v;
        else            ((unsigned short*)C)[coff + (size_t)(mb + r)*ldc + n] = f2bf(v);
      }
    }
  }
}

// ---------------------------------------------------------------------------
// gemm_bt: 128x128 tile, now BK=64, 4 waves, 2-phase dbuf, same swizzle.
// CMODE: 0 = f32 store (+bias), 1 = bf16 store (+bias), 2 = bf16 gelu(+bias)
// M,N mult 128; K mult 64. Batched over blockIdx.z.
// ---------------------------------------------------------------------------
template<int CMODE>
__global__ __launch_bounds__(256, 2)
void gemm_bt(const unsigned short* __restrict__ A, const unsigned short* __restrict__ B,
             void* __restrict__ C, const float* __restrict__ bias,
             int M, int N, int K, int lda, int ldb, int ldc,
             size_t aOffH, size_t aOffB, size_t bOffH, size_t bOffB,
             size_t cOffH, size_t cOffB)
{
  __shared__ unsigned short Ab[2][8192];    // [buf][128 rows][64 k]
  __shared__ unsigned short Bb[2][8192];

  const int m0 = blockIdx.y*128, n0 = blockIdx.x*128;
  const int z = blockIdx.z, bb = z >> 3, hh = z & 7;
  A += (size_t)bb*aOffB + (size_t)hh*aOffH;
  B += (size_t)bb*bOffB + (size_t)hh*bOffH;
  const size_t coff = (size_t)bb*cOffB + (size_t)hh*cOffH;

  const int tid = threadIdx.x, lane = tid & 63, w = tid >> 6;
  const int wr = w >> 1, wc = w & 1;
  const int l15 = lane & 15, l4 = lane >> 4;
  const int nt = K >> 6;

  const int r8  = tid >> 3;                 // 0..31
  const int sc8 = ((tid & 7) ^ (r8 & 7)) * 8;

  auto stage = [&](int buf, int kt){
    #pragma unroll
    for (int j = 0; j < 4; j++){
      gload16(A + (size_t)(m0 + j*32 + r8)*lda + kt + sc8, &Ab[buf][j*2048 + tid*8]);
      gload16(B + (size_t)(n0 + j*32 + r8)*ldb + kt + sc8, &Bb[buf][j*2048 + tid*8]);
    }
  };

  f32x4 acc[4][4] = {};

  stage(0, 0);
  __syncthreads();
  for (int t = 0; t < nt; t++){
    const int cur = t & 1;
    if (t + 1 < nt) stage(cur ^ 1, (t+1)*64);

    bf16x8 af[4][2], bfr[4][2];
    #pragma unroll
    for (int i = 0; i < 4; i++){
      const int Ra = wr*64 + i*16 + l15;
      const int Rb = wc*64 + i*16 + l15;
      #pragma unroll
      for (int kc = 0; kc < 2; kc++){
        const int ca = (kc*32 + l4*8) ^ ((Ra & 7) * 8);
        const int cb = (kc*32 + l4*8) ^ ((Rb & 7) * 8);
        af[i][kc]  = *(const bf16x8*)&Ab[cur][Ra*64 + ca];
        bfr[i][kc] = *(const bf16x8*)&Bb[cur][Rb*64 + cb];
      }
    }
    #pragma unroll
    for (int i = 0; i < 4; i++)
      #pragma unroll
      for (int jj = 0; jj < 4; jj++)
        #pragma unroll
        for (int kc = 0; kc < 2; kc++)
          acc[i][jj] = __builtin_amdgcn_mfma_f32_16x16x32_bf16(
              af[i][kc], bfr[jj][kc], acc[i][jj], 0, 0, 0);
    __syncthreads();
  }

  #pragma unroll
  for (int i = 0; i < 4; i++){
    const int mbase = m0 + wr*64 + i*16 + l4*4;
    #pragma unroll
    for (int jj = 0; jj < 4; jj++){
      const int n = n0 + wc*64 + jj*16 + l15;
      const float bv = bias ? bias[n] : 0.0f;
      #pragma unroll
      for (int r = 0; r < 4; r++){
        const int m = mbase + r;
        float v = acc[i][jj][r] + bv;
        if (CMODE == 0){
          ((float*)C)[coff + (size_t)m*ldc + n] = v;
        } else if (CMODE == 1){
          ((unsigned short*)C)[coff + (size_t)m*ldc + n] = f2bf(v);
        } else {
          v = 0.5f * v * (1.0f + erff(v * 0.70710678118654752f));   // exact GELU
          ((unsigned short*)C)[coff + (size_t)m*ldc + n] = f2bf(v);
        }
      }
    }
  }
}

// ---------------------------------------------------------------------------
template<int CAUSAL>
__global__ __launch_bounds__(256)
void softmax_rows(float* __restrict__ scores)
{
  const int row  = blockIdx.x*4 + (threadIdx.x >> 6);
  const int lane = threadIdx.x & 63;
  const int q = row & 511;
  const float* srow = scores + (size_t)row*512;
  float s[8]; float m = -1e30f;
  #pragma unroll
  for (int i = 0; i < 8; i++){
    const int col = lane*8 + i;
    float v = srow[col] * 0.044194173824159216f;   // 1/sqrt(512)
    if (CAUSAL && col > q) v = -1e30f;
    s[i] = v; m = fmaxf(m, v);
  }
  #pragma unroll
  for (int o = 32; o; o >>= 1) m = fmaxf(m, __shfl_xor(m, o));
  float p[8], sum = 0.f;
  #pragma unroll
  for (int i = 0; i < 8; i++){
    float e = __expf(s[i] - m);
    if (CAUSAL && (lane*8 + i) > q) e = 0.f;
    p[i] = e; sum += e;
  }
  #pragma unroll
  for (int o = 32; o; o >>= 1) sum += __shfl_xor(sum, o);
  const float inv = 1.0f / sum;
  unsigned short* prow = (unsigned short*)scores + (size_t)row*1024;
  #pragma unroll
  for (int i = 0; i < 8; i++) prow[lane*8 + i] = f2bf(p[i] * inv);
}

// ---------------------------------------------------------------------------
template<int WRITE_BF>
__global__ __launch_bounds__(256)
void ln_rows(const float* __restrict__ x, const float* __restrict__ d1,
             const float* __restrict__ d2, const float* __restrict__ bias,
             const float* __restrict__ g, const float* __restrict__ bta,
             float* __restrict__ xo, unsigned short* __restrict__ xb)
{
  const int row = blockIdx.x*4 + (threadIdx.x >> 6);
  const int lane = threadIdx.x & 63;
  const float* xr = x  + (size_t)row*512;
  const float* d1r = d1 + (size_t)row*512;
  const float* d2r = d2 ? d2 + (size_t)row*512 : nullptr;
  float v[8]; float sum = 0.f;
  #pragma unroll
  for (int i = 0; i < 8; i++){
    const int c = lane*8 + i;
    float t = xr[c] + d1r[c];
    if (d2) t += d2r[c];
    if (bias) t += bias[c];
    v[i] = t; sum += t;
  }
  #pragma unroll
  for (int o = 32; o; o >>= 1) sum += __shfl_xor(sum, o);
  const float mean = sum * (1.0f/512.0f);
  float s2 = 0.f;
  #pragma unroll
  for (int i = 0; i < 8; i++){ const float t = v[i] - mean; s2 += t*t; }
  #pragma unroll
  for (int o = 32; o; o >>= 1) s2 += __shfl_xor(s2, o);
  const float inv = rsqrtf(s2 * (1.0f/512.0f) + 1e-3f);
  #pragma unroll
  for (int i = 0; i < 8; i++){
    const int c = lane*8 + i;
    const float y = (v[i] - mean)*inv*g[c] + bta[c];
    xo[(size_t)row*512 + c] = y;
    if (WRITE_BF) xb[(size_t)row*512 + c] = f2bf(y);
  }
}

__global__ __launch_bounds__(256)
void cast_bf16_k(const float* __restrict__ s, unsigned short* __restrict__ d, int n)
{
  const int i = (blockIdx.x*256 + threadIdx.x)*4;
  if (i < n){
    const float4 v = *(const float4*)(s + i);
    uint2 o;
    o.x = (unsigned)f2bf(v.x) | ((unsigned)f2bf(v.y) << 16);
    o.y = (unsigned)f2bf(v.z) | ((unsigned)f2bf(v.w) << 16);
    *(uint2*)(d + i) = o;
  }
}

// src [R][C] f32 -> dst [C][R] bf16
__global__ __launch_bounds__(256)
void transpose_cast(const float* __restrict__ src, unsigned short* __restrict__ dst, int R, int C)
{
  __shared__ float tile[32][33];
  const int bx = blockIdx.x*32, by = blockIdx.y*32;
  const int tx = threadIdx.x, ty = threadIdx.y;
  #pragma unroll
  for (int i = 0; i < 32; i += 8) tile[ty + i][tx] = src[(size_t)(by + ty + i)*C + bx + tx];
  __syncthreads();
  #pragma unroll
  for (int i = 0; i < 32; i += 8) dst[(size_t)(bx + ty + i)*R + by + tx] = f2bf(tile[tx][ty + i]);
}

// vb [4096 m=(b,s)][4096 n=(h,ko)] bf16  ->  vT [b][h][ko][s] bf16
__global__ __launch_bounds__(256)
void transpose_v(const unsigned short* __restrict__ src, unsigned short* __restrict__ dst)
{
  __shared__ unsigned short t[32][34];
  const int z = blockIdx.z, b = z >> 3, h = z & 7;
  const int s0 = blockIdx.y*32, k0 = blockIdx.x*32;
  const int tx = threadIdx.x & 31, ty4 = (threadIdx.x >> 5) * 4;
  #pragma unroll
  for (int i = 0; i < 4; i++)
    t[ty4 + i][tx] = src[(size_t)(b*512 + s0 + ty4 + i)*4096 + h*512 + k0 + tx];
  __syncthreads();
  unsigned short* d = dst + ((size_t)z*512 + k0)*512 + s0;
  #pragma unroll
  for (int i = 0; i < 4; i++)
    d[(size_t)(ty4 + i)*512 + tx] = t[tx][ty4 + i];
}

// ---------------------------------------------------------------------------
extern "C" void kernel_launch(void* const* d_in, const int* in_sizes, int n_in,
                              void* d_out, int out_size, void* d_ws, size_t ws_size,
                              hipStream_t stream)
{
  (void)in_sizes; (void)n_in; (void)out_size; (void)ws_size;

  const float* in_seq  = (const float*)d_in[0];
  const float* out_seq = (const float*)d_in[1];
  const float* sa_wq = (const float*)d_in[2];  const float* sa_bq = (const float*)d_in[3];
  const float* sa_wk = (const float*)d_in[4];  const float* sa_bk = (const float*)d_in[5];
  const float* sa_wv = (const float*)d_in[6];  const float* sa_bv = (const float*)d_in[7];
  const float* sa_wo = (const float*)d_in[8];  const float* sa_bo = (const float*)d_in[9];
  const float* sa_lng = (const float*)d_in[10]; const float* sa_lnb = (const float*)d_in[11];
  const float* ca_wq = (const float*)d_in[12]; const float* ca_bq = (const float*)d_in[13];
  const float* ca_wk = (const float*)d_in[14]; const float* ca_bk = (const float*)d_in[15];
  const float* ca_wv = (const float*)d_in[16]; const float* ca_bv = (const float*)d_in[17];
  const float* ca_wo = (const float*)d_in[18]; const float* ca_bo = (const float*)d_in[19];
  const float* ca_lng = (const float*)d_in[20]; const float* ca_lnb = (const float*)d_in[21];
  const float* ff_w1 = (const float*)d_in[22]; const float* ff_b1 = (const float*)d_in[23];
  const float* ff_w2 = (const float*)d_in[24]; const float* ff_b2 = (const float*)d_in[25];
  const float* ff_lng = (const float*)d_in[26]; const float* ff_lnb = (const float*)d_in[27];

  char* ws = (char*)d_ws;
  size_t off = 0;
  auto alloc = [&](size_t bytes){ char* p = ws + off; off += (bytes + 255) & ~(size_t)255; return p; };

  unsigned short* wT[8];
  for (int i = 0; i < 8; i++) wT[i] = (unsigned short*)alloc(4096ULL*512*2);
  unsigned short* w1T  = (unsigned short*)alloc(1024ULL*512*2);
  unsigned short* w2T  = (unsigned short*)alloc(512ULL*1024*2);
  unsigned short* xbf  = (unsigned short*)alloc(4096ULL*512*2);
  unsigned short* inbf = (unsigned short*)alloc(4096ULL*512*2);
  unsigned short* qb   = (unsigned short*)alloc(4096ULL*4096*2);   // also FFN hidden
  unsigned short* kb   = (unsigned short*)alloc(4096ULL*4096*2);   // also attn-out
  unsigned short* vT   = (unsigned short*)alloc(64ULL*512*512*2);
  float*          sc   = (float*)alloc(64ULL*512*512*4);           // scores (+probs)
  float*          tmp  = (float*)alloc(4096ULL*512*4);
  float*          xcur = (float*)alloc(4096ULL*512*4);

  // vb / tmp2 alias the (temporally dead) scores region (see R2 post-mortem).
  unsigned short* vb   = (unsigned short*)sc;
  float*          tmp2 = (float*)sc;

  dim3 tb(32, 8);
  cast_bf16_k<<<2048, 256, 0, stream>>>(out_seq, xbf, 4096*512);
  cast_bf16_k<<<2048, 256, 0, stream>>>(in_seq, inbf, 4096*512);
  // weights -> [N][K] bf16
  transpose_cast<<<dim3(128,16), tb, 0, stream>>>(sa_wq, wT[0], 512, 4096);
  transpose_cast<<<dim3(128,16), tb, 0, stream>>>(sa_wk, wT[1], 512, 4096);
  transpose_cast<<<dim3(128,16), tb, 0, stream>>>(sa_wv, wT[2], 512, 4096);
  transpose_cast<<<dim3(16,128), tb, 0, stream>>>(sa_wo, wT[3], 4096, 512);
  transpose_cast<<<dim3(128,16), tb, 0, stream>>>(ca_wq, wT[4], 512, 4096);
  transpose_cast<<<dim3(128,16), tb, 0, stream>>>(ca_wk, wT[5], 512, 4096);
  transpose_cast<<<dim3(128,16), tb, 0, stream>>>(ca_wv, wT[6], 512, 4096);
  transpose_cast<<<dim3(16,128), tb, 0, stream>>>(ca_wo, wT[7], 4096, 512);
  transpose_cast<<<dim3(32,16),  tb, 0, stream>>>(ff_w1, w1T, 512, 1024);
  transpose_cast<<<dim3(16,32),  tb, 0, stream>>>(ff_w2, w2T, 1024, 512);

  #define GEMM(MODE, Apt, Bpt, Cpt, BIAS, M, N, K, LDA, LDB, LDC, Z, aH, aB, bH, bB, cH, cB) \
    gemm_bt<MODE><<<dim3((N)/128,(M)/128,(Z)), 256, 0, stream>>>( \
      (const unsigned short*)(Apt), (const unsigned short*)(Bpt), (void*)(Cpt), BIAS, \
      M, N, K, LDA, LDB, LDC, aH, aB, bH, bB, cH, cB)

  #define G256(MODE, CSK, Apt, Bpt, Cpt, BIAS, M, N, K, LDA, LDB, LDC, Z, aH, aB, bH, bB, cH, cB) \
    gemm256<MODE, CSK><<<dim3((N)/256,(M)/256,(Z)), 512, 0, stream>>>( \
      (const unsigned short*)(Apt), (const unsigned short*)(Bpt), (void*)(Cpt), BIAS, \
      M, N, K, LDA, LDB, LDC, aH, aB, bH, bB, cH, cB)

  // ---- self-attention (causal) ----
  G256(1, 0, xbf, wT[0], qb, sa_bq, 4096, 4096, 512, 512, 512, 4096, 1, 0,0,0,0,0,0);
  G256(1, 0, xbf, wT[1], kb, sa_bk, 4096, 4096, 512, 512, 512, 4096, 1, 0,0,0,0,0,0);
  G256(1, 0, xbf, wT[2], vb, sa_bv, 4096, 4096, 512, 512, 512, 4096, 1, 0,0,0,0,0,0);
  transpose_v<<<dim3(16,16,64), 256, 0, stream>>>(vb, vT);
  G256(0, 1, qb, kb, sc, nullptr, 512, 512, 512, 4096, 4096, 512, 64,
       512, 2097152, 512, 2097152, 262144, 2097152);
  softmax_rows<1><<<8192, 256, 0, stream>>>(sc);
  G256(1, 2, sc, vT, kb, nullptr, 512, 512, 512, 1024, 512, 4096, 64,
       524288, 4194304, 262144, 2097152, 512, 2097152);
  GEMM(0, kb, wT[3], tmp, nullptr, 4096, 512, 2048, 4096, 4096, 512, 2,
       2048, 0, 2048, 0, (size_t)(tmp2 - tmp), 0);
  ln_rows<1><<<1024, 256, 0, stream>>>(out_seq, tmp, tmp2, sa_bo, sa_lng, sa_lnb, xcur, xbf);

  // ---- cross-attention ----
  G256(1, 0, xbf,  wT[4], qb, ca_bq, 4096, 4096, 512, 512, 512, 4096, 1, 0,0,0,0,0,0);
  G256(1, 0, inbf, wT[5], kb, ca_bk, 4096, 4096, 512, 512, 512, 4096, 1, 0,0,0,0,0,0);
  G256(1, 0, inbf, wT[6], vb, ca_bv, 4096, 4096, 512, 512, 512, 4096, 1, 0,0,0,0,0,0);
  transpose_v<<<dim3(16,16,64), 256, 0, stream>>>(vb, vT);
  G256(0, 0, qb, kb, sc, nullptr, 512, 512, 512, 4096, 4096, 512, 64,
       512, 2097152, 512, 2097152, 262144, 2097152);
  softmax_rows<0><<<8192, 256, 0, stream>>>(sc);
  G256(1, 0, sc, vT, kb, nullptr, 512, 512, 512, 1024, 512, 4096, 64,
       524288, 4194304, 262144, 2097152, 512, 2097152);
  GEMM(0, kb, wT[7], tmp, nullptr, 4096, 512, 2048, 4096, 4096, 512, 2,
       2048, 0, 2048, 0, (size_t)(tmp2 - tmp), 0);
  ln_rows<1><<<1024, 256, 0, stream>>>(xcur, tmp, tmp2, ca_bo, ca_lng, ca_lnb, xcur, xbf);

  // ---- FFN ----
  GEMM(2, xbf, w1T, qb, ff_b1, 4096, 1024, 512, 512, 512, 1024, 1, 0,0,0,0,0,0);
  GEMM(0, qb, w2T, tmp, nullptr, 4096, 512, 512, 1024, 1024, 512, 2,
       512, 0, 512, 0, (size_t)(tmp2 - tmp), 0);
  ln_rows<0><<<1024, 256, 0, stream>>>(xcur, tmp, tmp2, ff_b2, ff_lng, ff_lnb, (float*)d_out, nullptr);

  #undef GEMM
  #undef G256
}